// Round 9
// baseline (876.011 us; speedup 1.0000x reference)
//
#include <hip/hip_runtime.h>
#include <math.h>

#define Nn     512
#define Ll     500
#define TSTEPS 800
#define NWG    64
#define NJ     8      // nodes per workgroup
#define NT     576    // 9 waves: wave0 control, waves 1-8 gather (one target per lane)
#define NEEG   64
#define NB_    40
#define NH_    20
#define SCALE_    524288.0f        // 2^19 fixed point
#define INVSCALE_ (1.0f/524288.0f)

// d_ws layout in floats
#define OFF_SUMSQ  0
#define OFF_ABORT  1                      // u32
#define OFF_ROWSUM 64                     // 512 f32
#define OFF_EEG    576                    // 2560 f32
#define OFF_ZEND   3200                   // zero [0, OFF_ZEND)
#define OFF_TBUF   3200                   // u32[3 * 64 * 512] producer-major tagged exchange
#define TBUF_WORDS (3*Nn*NWG)             // 98304
#define OFF_WS     (OFF_TBUF + TBUF_WORDS)
#define OFF_LMT    (OFF_WS + Nn*Nn)

__device__ __forceinline__ float relu_(float x) { return fmaxf(x, 0.0f); }
__device__ __forceinline__ int sext25_(unsigned u) { return ((int)(u << 7)) >> 7; }

__global__ void k_ws(const float* __restrict__ wbb, const float* __restrict__ sc,
                     float* __restrict__ ws)
{
    int i = blockIdx.x, tid = threadIdx.x;
    float rs = 0.f, sq = 0.f;
    for (int j = tid; j < Nn; j += 256) {
        float wij = expf(wbb[i*Nn+j]) * sc[i*Nn+j];
        float wji = expf(wbb[j*Nn+i]) * sc[j*Nn+i];
        float v = log1pf(0.5f*(wij + wji));
        ws[OFF_WS + i*Nn + j] = v;
        rs += v; sq += v*v;
    }
    #pragma unroll
    for (int off = 32; off > 0; off >>= 1) { rs += __shfl_down(rs, off); sq += __shfl_down(sq, off); }
    __shared__ float srs[4], ssq[4];
    int wv = tid >> 6, ln = tid & 63;
    if (ln == 0) { srs[wv] = rs; ssq[wv] = sq; }
    __syncthreads();
    if (tid == 0) {
        ws[OFF_ROWSUM + i] = srs[0]+srs[1]+srs[2]+srs[3];
        atomicAdd(&ws[OFF_SUMSQ], ssq[0]+ssq[1]+ssq[2]+ssq[3]);
    }
}

__global__ void k_lmt(const float* __restrict__ lm, float* __restrict__ ws)
{
    int n = blockIdx.x*256 + threadIdx.x;
    if (n >= Nn) return;
    float s = 0.f;
    for (int e = 0; e < NEEG; ++e) s += lm[e*Nn + n];
    float mean = s * (1.0f/NEEG);
    for (int e = 0; e < NEEG; ++e) ws[OFF_LMT + e*Nn + n] = lm[e*Nn + n] - mean;
}

__global__ __launch_bounds__(NT) void k_main(
    const float* __restrict__ input, const float* __restrict__ noise_in,
    const float* __restrict__ hx, const float* __restrict__ hE,
    const float* __restrict__ dist, const float* __restrict__ W_in,
    const float* __restrict__ theta, float* __restrict__ ws)
{
    __shared__ float hist[NJ][512];          // 16 KB circular E-history
    __shared__ float wn[NJ][Nn];             // 16 KB weights (full, incl. delay-0)
    __shared__ unsigned short dd[NJ][Nn];    //  8 KB delays
    __shared__ float u_l[TSTEPS*2];          // 6.4 KB stimulus
    __shared__ float lmt_l[NEEG][NJ];        //  2 KB
    __shared__ float eeg_l[NB_][NEEG];       // 10.2 KB
    __shared__ float eim[NJ];
    __shared__ unsigned abort_s;

    const int w   = blockIdx.x;
    const int tid = threadIdx.x;
    const int j0  = w*NJ;
    float* histf  = &hist[0][0];

    float th[16];
    #pragma unroll
    for (int k = 0; k < 16; ++k) th[k] = theta[k];
    const float kg   = 0.01f + relu_(th[0]);
    const float kc1  = 0.01f + relu_(th[1]);
    const float kc2  = 0.01f + relu_(th[2]);
    const float kc3  = 0.01f + relu_(th[3]);
    const float kc4  = 0.01f + relu_(th[4]);
    const float kstd = 150.0f + relu_(th[5]);
    const float rA   = relu_(th[6]);
    const float aa   = 1.0f + relu_(th[7]);
    const float rB   = relu_(th[8]);
    const float ab   = 1.0f + relu_(th[9]);
    const float vmax = th[10], v0p = th[11], rr = th[12];
    const float den  = 1.5f + relu_(th[15]);
    const float invnorm = 1.0f / sqrtf(ws[OFF_SUMSQ]);

    if (tid == 0) abort_s = 0u;

    for (int idx = tid; idx < NJ*Nn; idx += NT) {
        int jl = idx >> 9, i = idx & 511;
        int jg = j0 + jl;
        wn[jl][i] = ws[OFF_WS + jg*Nn + i] * invnorm;
        dd[jl][i] = (unsigned short)(int)(dist[jg*Nn + i] / den);
    }
    // slot s holds E(tau), s = tau mod 512; initial: tau=-1-k -> hE[:,k]
    for (int idx = tid; idx < NJ*512; idx += NT) {
        int jl = idx >> 9, s = idx & 511;
        int k = 511 - s;
        hist[jl][s] = (k < Ll) ? hE[(j0+jl)*Ll + k] : 0.0f;
    }
    for (int idx = tid; idx < TSTEPS*2; idx += NT) {
        int t = idx >> 1, s = idx & 1;
        int tt = (t % NH_)*NB_ + (t / NH_);
        u_l[idx] = input[tt*2 + s];
    }
    for (int idx = tid; idx < NEEG*NJ; idx += NT) {
        int e = idx / NJ, jl = idx - e*NJ;
        lmt_l[e][jl] = ws[OFF_LMT + e*Nn + j0 + jl];
    }
    // wave0 per-lane ODE state + params
    float stM=0,stE=0,stI=0,stMv=0,stEv=0,stIv=0, dgd_r=0, win0=0, win1=0;
    const float* nz_base = nullptr;
    if (tid < NJ) {
        stM  = hx[(j0+tid)*6+0]; stE  = hx[(j0+tid)*6+1]; stI  = hx[(j0+tid)*6+2];
        stMv = hx[(j0+tid)*6+3]; stEv = hx[(j0+tid)*6+4]; stIv = hx[(j0+tid)*6+5];
        dgd_r = -ws[OFF_ROWSUM + j0 + tid] * invnorm;
        win0 = W_in[(j0+tid)*2+0]; win1 = W_in[(j0+tid)*2+1];
        nz_base = noise_in + (size_t)(j0+tid)*(NH_*NB_*3);
    }
    __syncthreads();

    unsigned* tbuf   = (unsigned*)ws + OFF_TBUF;
    unsigned* abortf = (unsigned*)ws + OFF_ABORT;

    // gather-lane register preload + prologue publish (partials(0) -> buf0, tag0)
    // producer-major: word = buf*(NWG*512) + w*512 + target  (coalesced stores)
    float wnr[NJ];
    int   ofs[NJ];
    if (tid >= 64) {
        const int gt = tid - 64;
        float p = 0.f;
        #pragma unroll
        for (int jl = 0; jl < NJ; ++jl) {
            int d = (int)dd[jl][gt];
            wnr[jl] = wn[jl][gt];
            ofs[jl] = (0 - d) & 511;
            p += wnr[jl] * hist[jl][(511 - d) & 511];
        }
        __hip_atomic_store(&tbuf[w*512 + gt],
                           (unsigned)(int)lrintf(p*SCALE_) & 0x1FFFFFFu,
                           __ATOMIC_RELAXED, __HIP_MEMORY_SCOPE_AGENT);
    }

    int thc = 0, tbc = 0, bufc = 0;      // t%20, t/20, t%3
    for (int t = 0; t < TSTEPS; ++t) {
        // ---- pre-phase: pre-issue poll loads; positions are coupling-independent ----
        float nM_pre=0.f, nE_pre=0.f, nI_pre=0.f, nz=0.f;
        unsigned v0=0,v1=0,v2=0,v3=0,v4=0,v5=0,v6=0,v7=0;
        const unsigned* pb = nullptr;
        int pg8 = 0;
        if (tid < 64) {
            pg8 = (tid >> 3) * 8;                                  // producer group base
            pb  = tbuf + bufc*(Nn*NWG) + j0 + (tid & 7);
            v0 = __hip_atomic_load(&pb[(pg8+0)*512], __ATOMIC_RELAXED, __HIP_MEMORY_SCOPE_AGENT);
            v1 = __hip_atomic_load(&pb[(pg8+1)*512], __ATOMIC_RELAXED, __HIP_MEMORY_SCOPE_AGENT);
            v2 = __hip_atomic_load(&pb[(pg8+2)*512], __ATOMIC_RELAXED, __HIP_MEMORY_SCOPE_AGENT);
            v3 = __hip_atomic_load(&pb[(pg8+3)*512], __ATOMIC_RELAXED, __HIP_MEMORY_SCOPE_AGENT);
            v4 = __hip_atomic_load(&pb[(pg8+4)*512], __ATOMIC_RELAXED, __HIP_MEMORY_SCOPE_AGENT);
            v5 = __hip_atomic_load(&pb[(pg8+5)*512], __ATOMIC_RELAXED, __HIP_MEMORY_SCOPE_AGENT);
            v6 = __hip_atomic_load(&pb[(pg8+6)*512], __ATOMIC_RELAXED, __HIP_MEMORY_SCOPE_AGENT);
            v7 = __hip_atomic_load(&pb[(pg8+7)*512], __ATOMIC_RELAXED, __HIP_MEMORY_SCOPE_AGENT);
            if (tid < NJ) {
                nz = nz_base[(thc*NB_ + tbc)*3];                   // in flight across barrier
                nM_pre = stM + 0.05f*stMv;
                nE_pre = stE + 0.05f*stEv;
                nI_pre = stI + 0.05f*stIv;
                hist[tid][t & 511] = nE_pre;
                if (thc == NH_-1) eim[tid] = nE_pre - nI_pre;
            }
        }
        asm volatile("s_waitcnt lgkmcnt(0)" ::: "memory");   // drain LDS writes only
        __builtin_amdgcn_s_barrier();                        // vm ops stay in flight
        __builtin_amdgcn_sched_barrier(0);
        if (abort_s) break;                                  // set at previous step, uniform

        if (tid >= 64) {
            // ---- gather lanes: full partials (incl. d0) for step t+1 ----
            const int gt = tid - 64;
            float g = 0.f;
            #pragma unroll
            for (int jl = 0; jl < NJ; ++jl) {
                g += wnr[jl] * histf[jl*512 + ofs[jl]];
                ofs[jl] = (ofs[jl] + 1) & 511;
            }
            if (t < TSTEPS-1) {
                int bn = bufc + 1; if (bn == 3) bn = 0;
                unsigned* bufn = tbuf + bn*(Nn*NWG);
                __hip_atomic_store(&bufn[w*512 + gt],
                                   ((unsigned)((t+1) & 127) << 25) |
                                   ((unsigned)(int)lrintf(g*SCALE_) & 0x1FFFFFFu),
                                   __ATOMIC_RELAXED, __HIP_MEMORY_SCOPE_AGENT);
            }
            // wave 1: EEG dot at inner-scan boundary (reads eim written pre-B1)
            if (thc == NH_-1 && tid < 64 + NEEG) {
                int e = tid - 64;
                float s = 0.f;
                #pragma unroll
                for (int jl = 0; jl < NJ; ++jl) s += lmt_l[e][jl]*eim[jl];
                eeg_l[tbc][e] = s;
            }
        } else {
            // ---- control wave: ODE precompute under load shadow, tag check, reduce ----
            float stim=0.f, rE0=0.f, nMv=0.f, nIv=0.f;
            if (tid < NJ) {
                stim = win0*u_l[2*t] + win1*u_l[2*t+1];
                float rM  = vmax / (1.0f + expf(-rr*((stE - stI) - v0p)));
                float s1v = vmax / (1.0f + expf(-rr*((kc1*stM)  - v0p)));
                float s3v = vmax / (1.0f + expf(-rr*((kc3*stM)  - v0p)));
                float rI  = kc4*s3v;
                rE0 = kg*(dgd_r*stE) + kc2*s1v;
                nMv = stMv + 0.05f*(rA*aa*(500.0f*tanhf(rM*0.002f)) - 2.0f*aa*stMv - aa*aa*stM);
                nIv = stIv + 0.05f*(rB*ab*(500.0f*tanhf(rI*0.002f)) - 2.0f*ab*stIv - ab*ab*stI);
            }

            const unsigned tg = (unsigned)(t & 127);
            bool ok = ((v0>>25)==tg) && ((v1>>25)==tg) && ((v2>>25)==tg) && ((v3>>25)==tg)
                   && ((v4>>25)==tg) && ((v5>>25)==tg) && ((v6>>25)==tg) && ((v7>>25)==tg);
            unsigned spins = 0; bool to = false;
            while (!__all(ok)) {
                if (!ok) {
                    v0 = __hip_atomic_load(&pb[(pg8+0)*512], __ATOMIC_RELAXED, __HIP_MEMORY_SCOPE_AGENT);
                    v1 = __hip_atomic_load(&pb[(pg8+1)*512], __ATOMIC_RELAXED, __HIP_MEMORY_SCOPE_AGENT);
                    v2 = __hip_atomic_load(&pb[(pg8+2)*512], __ATOMIC_RELAXED, __HIP_MEMORY_SCOPE_AGENT);
                    v3 = __hip_atomic_load(&pb[(pg8+3)*512], __ATOMIC_RELAXED, __HIP_MEMORY_SCOPE_AGENT);
                    v4 = __hip_atomic_load(&pb[(pg8+4)*512], __ATOMIC_RELAXED, __HIP_MEMORY_SCOPE_AGENT);
                    v5 = __hip_atomic_load(&pb[(pg8+5)*512], __ATOMIC_RELAXED, __HIP_MEMORY_SCOPE_AGENT);
                    v6 = __hip_atomic_load(&pb[(pg8+6)*512], __ATOMIC_RELAXED, __HIP_MEMORY_SCOPE_AGENT);
                    v7 = __hip_atomic_load(&pb[(pg8+7)*512], __ATOMIC_RELAXED, __HIP_MEMORY_SCOPE_AGENT);
                    ok = ((v0>>25)==tg) && ((v1>>25)==tg) && ((v2>>25)==tg) && ((v3>>25)==tg)
                      && ((v4>>25)==tg) && ((v5>>25)==tg) && ((v6>>25)==tg) && ((v7>>25)==tg);
                }
                if ((++spins & 255u) == 0u) {
                    if (__hip_atomic_load(abortf, __ATOMIC_RELAXED, __HIP_MEMORY_SCOPE_AGENT) != 0u ||
                        spins > (1u<<18)) {
                        __hip_atomic_store(abortf, 1u, __ATOMIC_RELAXED, __HIP_MEMORY_SCOPE_AGENT);
                        to = true; break;
                    }
                }
            }
            if (to) {
                if (tid == 0) abort_s = 1u;     // all waves act on it after next barrier
            } else {
                int qs = sext25_(v0) + sext25_(v1) + sext25_(v2) + sext25_(v3)
                       + sext25_(v4) + sext25_(v5) + sext25_(v6) + sext25_(v7);
                qs += __shfl_xor(qs, 8);
                qs += __shfl_xor(qs, 16);
                qs += __shfl_xor(qs, 32);       // lanes with same (tid&7) hold total
                if (tid < NJ) {
                    float LEd = (float)qs * INVSCALE_;
                    float rE = rE0 + kstd*nz + kg*LEd;
                    float nEv = stEv + 0.05f*(rA*aa*(stim + 500.0f*tanhf(rE*0.002f)) - 2.0f*aa*stEv - aa*aa*stE);
                    stM = nM_pre; stE = nE_pre; stI = nI_pre;
                    stMv = nMv; stEv = nEv; stIv = nIv;
                }
            }
        }
        ++bufc; if (bufc == 3) bufc = 0;
        if (thc == NH_-1) { thc = 0; ++tbc; } else ++thc;
    }

    __syncthreads();
    if (abort_s == 0u) {
        const float* el = &eeg_l[0][0];
        for (int idx = tid; idx < NB_*NEEG; idx += NT)
            atomicAdd(&ws[OFF_EEG + idx], el[idx]);
    }
}

__global__ void k_out(const float* __restrict__ ws, const float* __restrict__ theta,
                      float* __restrict__ out)
{
    int idx = blockIdx.x*256 + threadIdx.x;
    if (idx < NB_*NEEG) out[idx] = 0.01f*theta[13]*ws[OFF_EEG + idx] - theta[14];
}

extern "C" void kernel_launch(void* const* d_in, const int* in_sizes, int n_in,
                              void* d_out, int out_size, void* d_ws, size_t ws_size,
                              hipStream_t stream)
{
    const float* input    = (const float*)d_in[0];
    const float* noise_in = (const float*)d_in[1];
    const float* hx       = (const float*)d_in[3];
    const float* hE       = (const float*)d_in[4];
    const float* sc       = (const float*)d_in[5];
    const float* dist     = (const float*)d_in[6];
    const float* w_bb     = (const float*)d_in[7];
    const float* W_in     = (const float*)d_in[8];
    const float* lm       = (const float*)d_in[10];
    const float* theta    = (const float*)d_in[11];
    float* ws  = (float*)d_ws;
    float* out = (float*)d_out;

    hipMemsetAsync(d_ws, 0, (size_t)OFF_ZEND*4, stream);                        // hdr+eeg
    hipMemsetAsync((char*)d_ws + (size_t)OFF_TBUF*4, 0xFF, (size_t)TBUF_WORDS*4, stream); // tags=127
    k_ws  <<<Nn, 256, 0, stream>>>(w_bb, sc, ws);
    k_lmt <<<(Nn + 255)/256, 256, 0, stream>>>(lm, ws);
    k_main<<<NWG, NT, 0, stream>>>(input, noise_in, hx, hE, dist, W_in, theta, ws);
    k_out <<<(NB_*NEEG + 255)/256, 256, 0, stream>>>(ws, theta, out);
}